// Round 1
// baseline (455.061 us; speedup 1.0000x reference)
//
#include <hip/hip_runtime.h>

#define B_ 8
#define C_ 512
#define H_ 32
#define W_ 32
#define L_ 1024
#define M_ 8192   // B*L
#define NH_ 8
#define HD_ 64

typedef float f32x4 __attribute__((ext_vector_type(4)));
typedef short s16x8 __attribute__((ext_vector_type(8)));

// MFMA via inline asm (gfx950 unified VGPR/AGPR file; v[] operands are valid).
// C/D layout: col = lane&15, row = (lane>>4)*4 + reg   [verified m89/m91]
// A frag:     row m = lane&15, k = (lane>>4)*8 + j (8 contiguous bf16)
// B frag (from B^T stored [N][K]): row n = lane&15, same k pattern.
__device__ __forceinline__ f32x4 mfma_bf16(f32x4 acc, s16x8 a, s16x8 b) {
    asm("v_mfma_f32_16x16x32_bf16 %0, %1, %2, %0" : "+v"(acc) : "v"(a), "v"(b));
    return acc;
}

__device__ __forceinline__ s16x8 ldg8(const unsigned short* p) {
    return *(const s16x8*)p;
}

// round-to-nearest-even f32 -> bf16 (inputs finite)
__device__ __forceinline__ unsigned short f2bf(float f) {
    unsigned int u = __float_as_uint(f);
    unsigned int r = (u + 0x7FFFu + ((u >> 16) & 1u)) >> 16;
    return (unsigned short)r;
}

__device__ __forceinline__ float gelu_exact(float v) {
    return 0.5f * v * (1.0f + erff(v * 0.70710678118654752f));
}

__device__ __forceinline__ float sigmoidf_(float v) {
    return 1.0f / (1.0f + __expf(-v));
}

// ---------------- K0: fp32 -> bf16 weight conversion (3 matrices) -------------
__global__ __launch_bounds__(256) void k_cvt_weights(
        const float* __restrict__ w1, const float* __restrict__ w2,
        const float* __restrict__ w3,
        unsigned short* __restrict__ o1, unsigned short* __restrict__ o2,
        unsigned short* __restrict__ o3, int n1, int n2, int n3) {
    int i = blockIdx.x * 256 + threadIdx.x;
    if (i < n1) o1[i] = f2bf(w1[i]);
    if (i < n2) o2[i] = f2bf(w2[i]);
    if (i < n3) o3[i] = f2bf(w3[i]);
}

// ---------------- K1: DualWalze (dw-conv x2 + mix + residual + BN + gelu) -----
// one block per (b,c) plane; 32x32 plane staged in LDS, circular wrap via &31
__global__ __launch_bounds__(256) void k_walze(
        const float* __restrict__ x, const float* __restrict__ dww,
        const float* __restrict__ dwb, const float* __restrict__ shw,
        const float* __restrict__ shb, const float* __restrict__ mixw,
        const float* __restrict__ gamma, const float* __restrict__ beta,
        float* __restrict__ xw) {
    __shared__ float tile[1024];
    int bc = blockIdx.x;           // b*C + c
    int c = bc & (C_ - 1);
    int tid = threadIdx.x;
    const float* xp = x + (size_t)bc * 1024;
#pragma unroll
    for (int t = 0; t < 4; ++t) tile[tid + 256 * t] = xp[tid + 256 * t];
    __syncthreads();
    float wm[9], wsh[9];
#pragma unroll
    for (int t = 0; t < 9; ++t) { wm[t] = dww[c * 9 + t]; wsh[t] = shw[t]; }
    float mix = sigmoidf_(mixw[0]);
    float bmain = dwb[c], bsh = shb[0];
    float g = gamma[c], bt = beta[c];
    const float rs = rsqrtf(1.0f + 1e-5f);
#pragma unroll
    for (int t = 0; t < 4; ++t) {
        int l = tid + 256 * t;
        int h = l >> 5, w = l & 31;
        float accm = 0.f, accs = 0.f;
#pragma unroll
        for (int kh = 0; kh < 3; ++kh) {
            int hh = (h + kh + 31) & 31;
#pragma unroll
            for (int kw = 0; kw < 3; ++kw) {
                int ww = (w + kw + 31) & 31;
                float v = tile[hh * 32 + ww];
                accm += v * wm[kh * 3 + kw];
                accs += v * wsh[kh * 3 + kw];
            }
        }
        float combined = mix * (accm + bmain) + (1.f - mix) * (accs + bsh) + tile[l];
        float bn = g * combined * rs + bt;
        xw[(size_t)bc * 1024 + l] = gelu_exact(bn);
    }
}

// ---------------- K2: pack [x, x_walze] into bf16 seq layout (B,L,2C) ---------
__global__ __launch_bounds__(256) void k_pack(
        const float* __restrict__ x, const float* __restrict__ xw,
        unsigned short* __restrict__ comb) {
    int bl = blockIdx.x;           // b*L + l
    int b = bl >> 10, l = bl & 1023;
    int tid = threadIdx.x;
    unsigned short* row = comb + (size_t)bl * 1024;
#pragma unroll
    for (int t = 0; t < 2; ++t) {
        int c = tid + 256 * t;
        size_t src = ((size_t)(b * C_ + c) << 10) + l;
        row[c] = f2bf(x[src]);
        row[512 + c] = f2bf(xw[src]);
    }
}

// ---------------- K3: spike detector fused (GEMM1+gelu+dot+sigmoid) ----------
// M-tile 16 per block; full N=128 split 32/wave; K=1024
__global__ __launch_bounds__(256) void k_detector(
        const unsigned short* __restrict__ comb, const unsigned short* __restrict__ w1,
        const float* __restrict__ b1, const float* __restrict__ w2,
        const float* __restrict__ b2, float* __restrict__ sm) {
    __shared__ float red[64];
    int tid = threadIdx.x;
    int wave = tid >> 6, lane = tid & 63;
    int col = lane & 15, quad = lane >> 4;
    int m0 = blockIdx.x * 16;
    int koff = quad * 8;
    int nb0 = wave * 32, nb1 = nb0 + 16;
    const unsigned short* pa  = comb + (size_t)(m0 + col) * 1024 + koff;
    const unsigned short* pw0 = w1 + (size_t)(nb0 + col) * 1024 + koff;
    const unsigned short* pw1 = w1 + (size_t)(nb1 + col) * 1024 + koff;
    f32x4 acc0 = {0.f, 0.f, 0.f, 0.f}, acc1 = {0.f, 0.f, 0.f, 0.f};
    for (int k = 0; k < 1024; k += 32) {
        s16x8 a = ldg8(pa + k);
        acc0 = mfma_bf16(acc0, a, ldg8(pw0 + k));
        acc1 = mfma_bf16(acc1, a, ldg8(pw1 + k));
    }
    asm volatile("s_nop 7\ns_nop 7");   // MFMA -> VALU read hazard cover
    float bia0 = b1[nb0 + col], bia1 = b1[nb1 + col];
    float wv0 = w2[nb0 + col], wv1 = w2[nb1 + col];
#pragma unroll
    for (int r = 0; r < 4; ++r) {
        float h0 = gelu_exact(acc0[r] + bia0);
        float h1 = gelu_exact(acc1[r] + bia1);
        float p = h0 * wv0 + h1 * wv1;
        p += __shfl_xor(p, 1);
        p += __shfl_xor(p, 2);
        p += __shfl_xor(p, 4);
        p += __shfl_xor(p, 8);
        if (col == 0) red[wave * 16 + quad * 4 + r] = p;
    }
    __syncthreads();
    if (tid < 16) {
        float s = red[tid] + red[16 + tid] + red[32 + tid] + red[48 + tid] + b2[0];
        sm[m0 + tid] = sigmoidf_(s);
    }
}

// ---------------- K4: qkv projection GEMM (M=8192,N=1536,K=512) --------------
// A = comb+512 (x_walze half), lda=1024; W = in_proj_w bf16 [1536][512]
__global__ __launch_bounds__(256) void k_gemm_qkv(
        const unsigned short* __restrict__ A, const unsigned short* __restrict__ Wt,
        const float* __restrict__ bias, float* __restrict__ out) {
    int tid = threadIdx.x;
    int wave = tid >> 6, lane = tid & 63;
    int col = lane & 15, quad = lane >> 4;
    int koff = quad * 8;
    int wr = wave & 1, wc = wave >> 1;
    int mb = blockIdx.y * 64 + wr * 32;
    int nb = blockIdx.x * 64 + wc * 32;
    const unsigned short* pa0 = A + (size_t)(mb + col) * 1024 + koff;
    const unsigned short* pa1 = pa0 + 16 * 1024;
    const unsigned short* pw0 = Wt + (size_t)(nb + col) * 512 + koff;
    const unsigned short* pw1 = pw0 + 16 * 512;
    f32x4 acc[2][2] = {};
    for (int k = 0; k < 512; k += 32) {
        s16x8 a0 = ldg8(pa0 + k), a1 = ldg8(pa1 + k);
        s16x8 w0 = ldg8(pw0 + k), w1 = ldg8(pw1 + k);
        acc[0][0] = mfma_bf16(acc[0][0], a0, w0);
        acc[0][1] = mfma_bf16(acc[0][1], a0, w1);
        acc[1][0] = mfma_bf16(acc[1][0], a1, w0);
        acc[1][1] = mfma_bf16(acc[1][1], a1, w1);
    }
    asm volatile("s_nop 7\ns_nop 7");
#pragma unroll
    for (int i2 = 0; i2 < 2; ++i2)
#pragma unroll
        for (int j2 = 0; j2 < 2; ++j2) {
            int n = nb + j2 * 16 + col;
            float bv = bias[n];
#pragma unroll
            for (int r = 0; r < 4; ++r) {
                int m = mb + i2 * 16 + quad * 4 + r;
                out[(size_t)m * 1536 + n] = acc[i2][j2][r] + bv;
            }
        }
}

// ---------------- K5: windowed attention, one wave per (b,h,i) row -----------
__global__ __launch_bounds__(256) void k_attn(
        const float* __restrict__ qkv, unsigned short* __restrict__ ctx) {
    int gr = blockIdx.x * 4 + (threadIdx.x >> 6);   // b*8192 + h*1024 + i
    int lane = threadIdx.x & 63;
    int b = gr >> 13, rem = gr & 8191;
    int h = rem >> 10, i = rem & 1023;
    const float* qrow = qkv + (size_t)(b * 1024 + i) * 1536 + h * 64;
    int jlo = max(i - 16, 0), jhi = min(i + 16, 1023);
    int cnt = jhi - jlo + 1;                         // <= 33
    float s = -1e30f;
    if (lane < cnt) {
        const float* krow = qkv + (size_t)(b * 1024 + jlo + lane) * 1536 + 512 + h * 64;
        float d = 0.f;
#pragma unroll
        for (int t = 0; t < 64; ++t) d += qrow[t] * krow[t];
        s = d * 0.125f;                              // 1/sqrt(64)
    }
    float mx = s;
#pragma unroll
    for (int off = 32; off; off >>= 1) mx = fmaxf(mx, __shfl_xor(mx, off));
    float p = (lane < cnt) ? __expf(s - mx) : 0.f;
    float sum = p;
#pragma unroll
    for (int off = 32; off; off >>= 1) sum += __shfl_xor(sum, off);
    float inv = 1.f / sum;
    const float* vcol = qkv + (size_t)(b * 1024 + jlo) * 1536 + 1024 + h * 64 + lane;
    float cv = 0.f;
    for (int t = 0; t < cnt; ++t) cv += __shfl(p, t) * vcol[(size_t)t * 1536];
    cv *= inv;
    ctx[(size_t)(b * 1024 + i) * 512 + h * 64 + lane] = f2bf(cv);
}

// ---------------- K6: out-proj GEMM + gated residual combine -----------------
// A = ctx bf16 [8192][512]; W = out_proj_w bf16 [512][512]
// out[b][c][l] = xw[b][c][l] + smask[b*L+l] * (ctx@W^T + bias)[b*L+l][c]
__global__ __launch_bounds__(256) void k_gemm_out_combine(
        const unsigned short* __restrict__ A, const unsigned short* __restrict__ Wt,
        const float* __restrict__ bias, const float* __restrict__ xw,
        const float* __restrict__ sm, float* __restrict__ out) {
    int tid = threadIdx.x;
    int wave = tid >> 6, lane = tid & 63;
    int col = lane & 15, quad = lane >> 4;
    int koff = quad * 8;
    int wr = wave & 1, wc = wave >> 1;
    int mb = blockIdx.y * 64 + wr * 32;
    int nb = blockIdx.x * 64 + wc * 32;
    const unsigned short* pa0 = A + (size_t)(mb + col) * 512 + koff;
    const unsigned short* pa1 = pa0 + 16 * 512;
    const unsigned short* pw0 = Wt + (size_t)(nb + col) * 512 + koff;
    const unsigned short* pw1 = pw0 + 16 * 512;
    f32x4 acc[2][2] = {};
    for (int k = 0; k < 512; k += 32) {
        s16x8 a0 = ldg8(pa0 + k), a1 = ldg8(pa1 + k);
        s16x8 w0 = ldg8(pw0 + k), w1 = ldg8(pw1 + k);
        acc[0][0] = mfma_bf16(acc[0][0], a0, w0);
        acc[0][1] = mfma_bf16(acc[0][1], a0, w1);
        acc[1][0] = mfma_bf16(acc[1][0], a1, w0);
        acc[1][1] = mfma_bf16(acc[1][1], a1, w1);
    }
    asm volatile("s_nop 7\ns_nop 7");
#pragma unroll
    for (int i2 = 0; i2 < 2; ++i2)
#pragma unroll
        for (int j2 = 0; j2 < 2; ++j2) {
            int n = nb + j2 * 16 + col;     // output channel c
            float bv = bias[n];
#pragma unroll
            for (int r = 0; r < 4; ++r) {
                int m = mb + i2 * 16 + quad * 4 + r;   // b*L + l
                int b = m >> 10, l = m & 1023;
                float v = acc[i2][j2][r] + bv;
                size_t oidx = ((size_t)(b * C_ + n) << 10) + l;
                out[oidx] = xw[oidx] + sm[m] * v;
            }
        }
}

extern "C" void kernel_launch(void* const* d_in, const int* in_sizes, int n_in,
                              void* d_out, int out_size, void* d_ws, size_t ws_size,
                              hipStream_t stream) {
    const float* x      = (const float*)d_in[0];
    const float* dw_w   = (const float*)d_in[1];
    const float* dw_b   = (const float*)d_in[2];
    const float* sh_w   = (const float*)d_in[3];
    const float* sh_b   = (const float*)d_in[4];
    const float* mix_w  = (const float*)d_in[5];
    const float* bn_g   = (const float*)d_in[6];
    const float* bn_b   = (const float*)d_in[7];
    const float* det_w1 = (const float*)d_in[8];
    const float* det_b1 = (const float*)d_in[9];
    const float* det_w2 = (const float*)d_in[10];
    const float* det_b2 = (const float*)d_in[11];
    const float* inp_w  = (const float*)d_in[12];
    const float* inp_b  = (const float*)d_in[13];
    const float* outp_w = (const float*)d_in[14];
    const float* outp_b = (const float*)d_in[15];
    float* out = (float*)d_out;

    char* ws = (char*)d_ws;
    size_t off = 0;
    auto alloc = [&](size_t bytes) -> void* {
        void* p = ws + off;
        off += (bytes + 255) & ~(size_t)255;
        return p;
    };
    float* xw             = (float*)alloc((size_t)M_ * C_ * 4);        // 16 MB spatial x_walze
    unsigned short* comb  = (unsigned short*)alloc((size_t)M_ * 1024 * 2); // 16 MB bf16 [x|xw] seq
    float* qkv            = (float*)alloc((size_t)M_ * 1536 * 4);      // 48 MB fp32
    unsigned short* ctx   = (unsigned short*)alloc((size_t)M_ * 512 * 2);  // 8 MB bf16
    float* smask          = (float*)alloc((size_t)M_ * 4);
    unsigned short* w1b   = (unsigned short*)alloc(131072 * 2);
    unsigned short* inwb  = (unsigned short*)alloc(786432 * 2);
    unsigned short* outwb = (unsigned short*)alloc(262144 * 2);
    (void)ws_size; (void)in_sizes; (void)n_in; (void)out_size;

    k_cvt_weights<<<3072, 256, 0, stream>>>(det_w1, inp_w, outp_w, w1b, inwb, outwb,
                                            131072, 786432, 262144);
    k_walze<<<B_ * C_, 256, 0, stream>>>(x, dw_w, dw_b, sh_w, sh_b, mix_w, bn_g, bn_b, xw);
    k_pack<<<M_, 256, 0, stream>>>(x, xw, comb);
    k_detector<<<M_ / 16, 256, 0, stream>>>(comb, w1b, det_b1, det_w2, det_b2, smask);
    k_gemm_qkv<<<dim3(1536 / 64, M_ / 64), 256, 0, stream>>>(comb + 512, inwb, inp_b, qkv);
    k_attn<<<M_ * NH_ / 4, 256, 0, stream>>>(qkv, ctx);
    k_gemm_out_combine<<<dim3(512 / 64, M_ / 64), 256, 0, stream>>>(ctx, outwb, outp_b,
                                                                    xw, smask, out);
}

// Round 2
// 315.177 us; speedup vs baseline: 1.4438x; 1.4438x over previous
//
#include <hip/hip_runtime.h>

#define B_ 8
#define C_ 512
#define H_ 32
#define W_ 32
#define L_ 1024
#define M_ 8192   // B*L
#define NH_ 8
#define HD_ 64

typedef float f32x4 __attribute__((ext_vector_type(4)));
typedef short s16x8 __attribute__((ext_vector_type(8)));

// MFMA 16x16x32 bf16. C/D: col=lane&15 (n), row=(lane>>4)*4+reg (m).
// A frag: row m=lane&15, k=(lane>>4)*8+j ; B frag from B^T [n][k]: row n=lane&15.
__device__ __forceinline__ f32x4 mfma_bf16(f32x4 acc, s16x8 a, s16x8 b) {
    asm("v_mfma_f32_16x16x32_bf16 %0, %1, %2, %0" : "+v"(acc) : "v"(a), "v"(b));
    return acc;
}

__device__ __forceinline__ s16x8 ldg8(const unsigned short* p) {
    return *(const s16x8*)p;
}

__device__ __forceinline__ unsigned short f2bf(float f) {
    unsigned int u = __float_as_uint(f);
    unsigned int r = (u + 0x7FFFu + ((u >> 16) & 1u)) >> 16;
    return (unsigned short)r;
}

__device__ __forceinline__ float gelu_exact(float v) {
    return 0.5f * v * (1.0f + erff(v * 0.70710678118654752f));
}

__device__ __forceinline__ float sigmoidf_(float v) {
    return 1.0f / (1.0f + __expf(-v));
}

// ---------------- K0: fp32 -> bf16 weight conversion --------------------------
__global__ __launch_bounds__(256) void k_cvt_weights(
        const float* __restrict__ w1, const float* __restrict__ w2,
        const float* __restrict__ w3,
        unsigned short* __restrict__ o1, unsigned short* __restrict__ o2,
        unsigned short* __restrict__ o3, int n1, int n2, int n3) {
    int i = blockIdx.x * 256 + threadIdx.x;
    if (i < n1) o1[i] = f2bf(w1[i]);
    if (i < n2) o2[i] = f2bf(w2[i]);
    if (i < n3) o3[i] = f2bf(w3[i]);
}

// ---------------- K1: DualWalze -----------------------------------------------
__global__ __launch_bounds__(256) void k_walze(
        const float* __restrict__ x, const float* __restrict__ dww,
        const float* __restrict__ dwb, const float* __restrict__ shw,
        const float* __restrict__ shb, const float* __restrict__ mixw,
        const float* __restrict__ gamma, const float* __restrict__ beta,
        float* __restrict__ xw) {
    __shared__ float tile[1024];
    int bc = blockIdx.x;           // b*C + c
    int c = bc & (C_ - 1);
    int tid = threadIdx.x;
    const float* xp = x + (size_t)bc * 1024;
#pragma unroll
    for (int t = 0; t < 4; ++t) tile[tid + 256 * t] = xp[tid + 256 * t];
    __syncthreads();
    float wm[9], wsh[9];
#pragma unroll
    for (int t = 0; t < 9; ++t) { wm[t] = dww[c * 9 + t]; wsh[t] = shw[t]; }
    float mix = sigmoidf_(mixw[0]);
    float bmain = dwb[c], bsh = shb[0];
    float g = gamma[c], bt = beta[c];
    const float rs = rsqrtf(1.0f + 1e-5f);
#pragma unroll
    for (int t = 0; t < 4; ++t) {
        int l = tid + 256 * t;
        int h = l >> 5, w = l & 31;
        float accm = 0.f, accs = 0.f;
#pragma unroll
        for (int kh = 0; kh < 3; ++kh) {
            int hh = (h + kh + 31) & 31;
#pragma unroll
            for (int kw = 0; kw < 3; ++kw) {
                int ww = (w + kw + 31) & 31;
                float v = tile[hh * 32 + ww];
                accm += v * wm[kh * 3 + kw];
                accs += v * wsh[kh * 3 + kw];
            }
        }
        float combined = mix * (accm + bmain) + (1.f - mix) * (accs + bsh) + tile[l];
        float bn = g * combined * rs + bt;
        xw[(size_t)bc * 1024 + l] = gelu_exact(bn);
    }
}

// ---------------- K2: LDS-tiled transpose+pack to bf16 seq layout -------------
// x,xw: [b][c][l] fp32 -> comb: [b][l][ x(512) | xw(512) ] bf16
__global__ __launch_bounds__(256) void k_pack(
        const float* __restrict__ x, const float* __restrict__ xw,
        unsigned short* __restrict__ comb) {
    __shared__ float Tx[64 * 65];
    __shared__ float Tw[64 * 65];
    int b = blockIdx.z;
    int c0 = blockIdx.y * 64;
    int l0 = blockIdx.x * 64;
    int tid = threadIdx.x;
    // load 64 c-rows x 64 l-cols, coalesced along l
    for (int idx = tid; idx < 1024; idx += 256) {
        int cr = idx >> 4, f = idx & 15;
        size_t src = ((size_t)(b * C_ + c0 + cr) << 10) + l0 + f * 4;
        float4 vx = *(const float4*)(x + src);
        float4 vw = *(const float4*)(xw + src);
        *(float4*)&Tx[cr * 65 + f * 4] = vx;
        *(float4*)&Tw[cr * 65 + f * 4] = vw;
    }
    __syncthreads();
    // write 64 l-rows x 64 c-cols, coalesced along c (ushort4 = 8B/lane)
    for (int idx = tid; idx < 1024; idx += 256) {
        int lr = idx >> 4, f = idx & 15;
        ushort4 ux, uw;
        ux.x = f2bf(Tx[(4 * f + 0) * 65 + lr]);
        ux.y = f2bf(Tx[(4 * f + 1) * 65 + lr]);
        ux.z = f2bf(Tx[(4 * f + 2) * 65 + lr]);
        ux.w = f2bf(Tx[(4 * f + 3) * 65 + lr]);
        uw.x = f2bf(Tw[(4 * f + 0) * 65 + lr]);
        uw.y = f2bf(Tw[(4 * f + 1) * 65 + lr]);
        uw.z = f2bf(Tw[(4 * f + 2) * 65 + lr]);
        uw.w = f2bf(Tw[(4 * f + 3) * 65 + lr]);
        unsigned short* row = comb + (((size_t)(b << 10) + l0 + lr) << 10);
        *(ushort4*)(row + c0 + 4 * f) = ux;
        *(ushort4*)(row + 512 + c0 + 4 * f) = uw;
    }
}

// ---------------- K3: spike detector fused ------------------------------------
__global__ __launch_bounds__(256) void k_detector(
        const unsigned short* __restrict__ comb, const unsigned short* __restrict__ w1,
        const float* __restrict__ b1, const float* __restrict__ w2,
        const float* __restrict__ b2, float* __restrict__ sm) {
    __shared__ float red[64];
    int tid = threadIdx.x;
    int wave = tid >> 6, lane = tid & 63;
    int col = lane & 15, quad = lane >> 4;
    int m0 = blockIdx.x * 16;
    int koff = quad * 8;
    int nb0 = wave * 32, nb1 = nb0 + 16;
    const unsigned short* pa  = comb + (size_t)(m0 + col) * 1024 + koff;
    const unsigned short* pw0 = w1 + (size_t)(nb0 + col) * 1024 + koff;
    const unsigned short* pw1 = w1 + (size_t)(nb1 + col) * 1024 + koff;
    f32x4 acc0 = {0.f, 0.f, 0.f, 0.f}, acc1 = {0.f, 0.f, 0.f, 0.f};
    for (int k = 0; k < 1024; k += 32) {
        s16x8 a = ldg8(pa + k);
        acc0 = mfma_bf16(acc0, a, ldg8(pw0 + k));
        acc1 = mfma_bf16(acc1, a, ldg8(pw1 + k));
    }
    asm volatile("s_nop 7\ns_nop 7");
    float bia0 = b1[nb0 + col], bia1 = b1[nb1 + col];
    float wv0 = w2[nb0 + col], wv1 = w2[nb1 + col];
#pragma unroll
    for (int r = 0; r < 4; ++r) {
        float h0 = gelu_exact(acc0[r] + bia0);
        float h1 = gelu_exact(acc1[r] + bia1);
        float p = h0 * wv0 + h1 * wv1;
        p += __shfl_xor(p, 1);
        p += __shfl_xor(p, 2);
        p += __shfl_xor(p, 4);
        p += __shfl_xor(p, 8);
        if (col == 0) red[wave * 16 + quad * 4 + r] = p;
    }
    __syncthreads();
    if (tid < 16) {
        float s = red[tid] + red[16 + tid] + red[32 + tid] + red[48 + tid] + b2[0];
        sm[m0 + tid] = sigmoidf_(s);
    }
}

// ---------------- K4: qkv GEMM, 128x128 block, 64x64/wave ---------------------
__global__ __launch_bounds__(256) void k_gemm_qkv(
        const unsigned short* __restrict__ A, const unsigned short* __restrict__ Wt,
        const float* __restrict__ bias, float* __restrict__ out) {
    int tid = threadIdx.x;
    int wave = tid >> 6, lane = tid & 63;
    int col = lane & 15, quad = lane >> 4;
    int koff = quad * 8;
    int wr = wave & 1, wc = wave >> 1;
    int mb = blockIdx.y * 128 + wr * 64;
    int nb = blockIdx.x * 128 + wc * 64;
    const unsigned short* pa = A + (size_t)(mb + col) * 1024 + koff;
    const unsigned short* pw = Wt + (size_t)(nb + col) * 512 + koff;
    f32x4 acc[4][4] = {};
    for (int k = 0; k < 512; k += 32) {
        s16x8 a[4], w[4];
#pragma unroll
        for (int i = 0; i < 4; ++i) a[i] = ldg8(pa + (size_t)i * 16 * 1024 + k);
#pragma unroll
        for (int j = 0; j < 4; ++j) w[j] = ldg8(pw + (size_t)j * 16 * 512 + k);
#pragma unroll
        for (int i = 0; i < 4; ++i)
#pragma unroll
            for (int j = 0; j < 4; ++j)
                acc[i][j] = mfma_bf16(acc[i][j], a[i], w[j]);
    }
    asm volatile("s_nop 7\ns_nop 7");
#pragma unroll
    for (int i2 = 0; i2 < 4; ++i2)
#pragma unroll
        for (int j2 = 0; j2 < 4; ++j2) {
            int n = nb + j2 * 16 + col;
            float bv = bias[n];
#pragma unroll
            for (int r = 0; r < 4; ++r) {
                int m = mb + i2 * 16 + quad * 4 + r;
                out[(size_t)m * 1536 + n] = acc[i2][j2][r] + bv;
            }
        }
}

// ---------------- K5: windowed attention, LDS-staged K/V ----------------------
// block = (qtile 64, head, batch); K transposed [d][key] (pad 97), V [key][d]
__global__ __launch_bounds__(256) void k_attn(
        const float* __restrict__ qkv, unsigned short* __restrict__ ctx) {
    __shared__ float Kt[64 * 97];   // 24.25 KB
    __shared__ float Vs[96 * 64];   // 24 KB
    int b = blockIdx.z, h = blockIdx.y;
    int q0 = blockIdx.x * 64;
    int tid = threadIdx.x;
    int jlo_t = max(q0 - 16, 0);
    int jhi_t = min(q0 + 63 + 16, 1023);
    int nrows = jhi_t - jlo_t + 1;            // 80 or 96
    // stage K (transposed) and V
    for (int idx = tid; idx < nrows * 16; idx += 256) {
        int r = idx >> 4, f = idx & 15;
        const float* rowp = qkv + (size_t)((b << 10) + jlo_t + r) * 1536 + h * 64 + f * 4;
        float4 kv = *(const float4*)(rowp + 512);
        float4 vv = *(const float4*)(rowp + 1024);
        Kt[(4 * f + 0) * 97 + r] = kv.x;
        Kt[(4 * f + 1) * 97 + r] = kv.y;
        Kt[(4 * f + 2) * 97 + r] = kv.z;
        Kt[(4 * f + 3) * 97 + r] = kv.w;
        *(float4*)&Vs[r * 64 + 4 * f] = vv;
    }
    __syncthreads();
    int wave = tid >> 6, lane = tid & 63;
    for (int qi = 0; qi < 16; ++qi) {
        int i = q0 + wave * 16 + qi;
        int jlo = max(i - 16, 0), jhi = min(i + 16, 1023);
        int cnt = jhi - jlo + 1;              // 17..33
        int jbase = jlo - jlo_t;              // 0..63
        const float* qg = qkv + (size_t)((b << 10) + i) * 1536 + h * 64;
        int kk = min(jbase + lane, 95);
        float a0 = 0.f, a1 = 0.f, a2 = 0.f, a3 = 0.f;
#pragma unroll
        for (int d = 0; d < 64; d += 4) {
            float4 qv = *(const float4*)(qg + d);
            a0 += qv.x * Kt[(d + 0) * 97 + kk];
            a1 += qv.y * Kt[(d + 1) * 97 + kk];
            a2 += qv.z * Kt[(d + 2) * 97 + kk];
            a3 += qv.w * Kt[(d + 3) * 97 + kk];
        }
        bool act = lane < cnt;
        float s = act ? ((a0 + a1) + (a2 + a3)) * 0.125f : -1e30f;
        float mx = s;
#pragma unroll
        for (int off = 32; off; off >>= 1) mx = fmaxf(mx, __shfl_xor(mx, off));
        float p = act ? __expf(s - mx) : 0.f;
        float sum = p;
#pragma unroll
        for (int off = 32; off; off >>= 1) sum += __shfl_xor(sum, off);
        float inv = 1.f / sum;
        float acc = 0.f;
        for (int t = 0; t < cnt; ++t)
            acc += __shfl(p, t) * Vs[(jbase + t) * 64 + lane];
        ctx[(size_t)((b << 10) + i) * 512 + h * 64 + lane] = f2bf(acc * inv);
    }
}

// ---------------- K6: out-proj GEMM (operand-swapped) + gated combine ---------
// M-dim = channel c (A = W [512][512]); N-dim = seq m (B = ctx [8192][512])
// -> C col = seq => stores & xw reads coalesced along l
__global__ __launch_bounds__(256) void k_gemm_out_combine(
        const unsigned short* __restrict__ Wt, const unsigned short* __restrict__ Actx,
        const float* __restrict__ bias, const float* __restrict__ xw,
        const float* __restrict__ sm, float* __restrict__ out) {
    int tid = threadIdx.x;
    int wave = tid >> 6, lane = tid & 63;
    int col = lane & 15, quad = lane >> 4;
    int koff = quad * 8;
    int wr = wave & 1, wc = wave >> 1;
    int cb = blockIdx.y * 64 + wr * 32;      // channel tile
    int sb = blockIdx.x * 64 + wc * 32;      // sequence tile
    const unsigned short* pa0 = Wt + (size_t)(cb + col) * 512 + koff;
    const unsigned short* pa1 = pa0 + 16 * 512;
    const unsigned short* pb0 = Actx + (size_t)(sb + col) * 512 + koff;
    const unsigned short* pb1 = pb0 + 16 * 512;
    f32x4 acc[2][2] = {};
    for (int k = 0; k < 512; k += 32) {
        s16x8 a0 = ldg8(pa0 + k), a1 = ldg8(pa1 + k);
        s16x8 b0 = ldg8(pb0 + k), b1 = ldg8(pb1 + k);
        acc[0][0] = mfma_bf16(acc[0][0], a0, b0);
        acc[0][1] = mfma_bf16(acc[0][1], a0, b1);
        acc[1][0] = mfma_bf16(acc[1][0], a1, b0);
        acc[1][1] = mfma_bf16(acc[1][1], a1, b1);
    }
    asm volatile("s_nop 7\ns_nop 7");
#pragma unroll
    for (int i2 = 0; i2 < 2; ++i2)
#pragma unroll
        for (int j2 = 0; j2 < 2; ++j2) {
            int seq = sb + j2 * 16 + col;
            int bb = seq >> 10, l = seq & 1023;
            float smv = sm[seq];
#pragma unroll
            for (int r = 0; r < 4; ++r) {
                int c = cb + i2 * 16 + quad * 4 + r;
                float v = acc[i2][j2][r] + bias[c];
                size_t oidx = ((size_t)(bb * C_ + c) << 10) + l;
                out[oidx] = xw[oidx] + smv * v;
            }
        }
}

extern "C" void kernel_launch(void* const* d_in, const int* in_sizes, int n_in,
                              void* d_out, int out_size, void* d_ws, size_t ws_size,
                              hipStream_t stream) {
    const float* x      = (const float*)d_in[0];
    const float* dw_w   = (const float*)d_in[1];
    const float* dw_b   = (const float*)d_in[2];
    const float* sh_w   = (const float*)d_in[3];
    const float* sh_b   = (const float*)d_in[4];
    const float* mix_w  = (const float*)d_in[5];
    const float* bn_g   = (const float*)d_in[6];
    const float* bn_b   = (const float*)d_in[7];
    const float* det_w1 = (const float*)d_in[8];
    const float* det_b1 = (const float*)d_in[9];
    const float* det_w2 = (const float*)d_in[10];
    const float* det_b2 = (const float*)d_in[11];
    const float* inp_w  = (const float*)d_in[12];
    const float* inp_b  = (const float*)d_in[13];
    const float* outp_w = (const float*)d_in[14];
    const float* outp_b = (const float*)d_in[15];
    float* out = (float*)d_out;

    char* ws = (char*)d_ws;
    size_t off = 0;
    auto alloc = [&](size_t bytes) -> void* {
        void* p = ws + off;
        off += (bytes + 255) & ~(size_t)255;
        return p;
    };
    float* xw             = (float*)alloc((size_t)M_ * C_ * 4);
    unsigned short* comb  = (unsigned short*)alloc((size_t)M_ * 1024 * 2);
    float* qkv            = (float*)alloc((size_t)M_ * 1536 * 4);
    unsigned short* ctx   = (unsigned short*)alloc((size_t)M_ * 512 * 2);
    float* smask          = (float*)alloc((size_t)M_ * 4);
    unsigned short* w1b   = (unsigned short*)alloc(131072 * 2);
    unsigned short* inwb  = (unsigned short*)alloc(786432 * 2);
    unsigned short* outwb = (unsigned short*)alloc(262144 * 2);
    (void)ws_size; (void)in_sizes; (void)n_in; (void)out_size;

    k_cvt_weights<<<3072, 256, 0, stream>>>(det_w1, inp_w, outp_w, w1b, inwb, outwb,
                                            131072, 786432, 262144);
    k_walze<<<B_ * C_, 256, 0, stream>>>(x, dw_w, dw_b, sh_w, sh_b, mix_w, bn_g, bn_b, xw);
    k_pack<<<dim3(16, 8, 8), 256, 0, stream>>>(x, xw, comb);
    k_detector<<<M_ / 16, 256, 0, stream>>>(comb, w1b, det_b1, det_w2, det_b2, smask);
    k_gemm_qkv<<<dim3(1536 / 128, M_ / 128), 256, 0, stream>>>(comb + 512, inwb, inp_b, qkv);
    k_attn<<<dim3(16, NH_, B_), 256, 0, stream>>>(qkv, ctx);
    k_gemm_out_combine<<<dim3(M_ / 64, C_ / 64), 256, 0, stream>>>(outwb, ctx, outp_b,
                                                                   xw, smask, out);
}

// Round 4
// 199.769 us; speedup vs baseline: 2.2779x; 1.5777x over previous
//
#include <hip/hip_runtime.h>

#define B_ 8
#define C_ 512
#define H_ 32
#define W_ 32
#define L_ 1024
#define M_ 8192   // B*L
#define NH_ 8
#define HD_ 64

typedef float f32x4 __attribute__((ext_vector_type(4)));
typedef short s16x8 __attribute__((ext_vector_type(8)));

// MFMA 16x16x32 bf16. C/D: col=lane&15 (n), row=(lane>>4)*4+reg (m).
// A frag: row m=lane&15, k=(lane>>4)*8+j ; B frag from B^T [n][k]: row n=lane&15.
__device__ __forceinline__ f32x4 mfma_bf16(f32x4 acc, s16x8 a, s16x8 b) {
    asm("v_mfma_f32_16x16x32_bf16 %0, %1, %2, %0" : "+v"(acc) : "v"(a), "v"(b));
    return acc;
}

__device__ __forceinline__ s16x8 ldg8(const unsigned short* p) {
    return *(const s16x8*)p;
}

typedef __attribute__((address_space(1))) const unsigned int glob_u32;
typedef __attribute__((address_space(3))) unsigned int lds_u32;
__device__ __forceinline__ void async_cp16(const void* g, void* l) {
    __builtin_amdgcn_global_load_lds((glob_u32*)g, (lds_u32*)l, 16, 0, 0);
}

__device__ __forceinline__ unsigned short f2bf(float f) {
    unsigned int u = __float_as_uint(f);
    unsigned int r = (u + 0x7FFFu + ((u >> 16) & 1u)) >> 16;
    return (unsigned short)r;
}

__device__ __forceinline__ float bf2f(unsigned short u) {
    return __uint_as_float(((unsigned int)u) << 16);
}

__device__ __forceinline__ float gelu_exact(float v) {
    return 0.5f * v * (1.0f + erff(v * 0.70710678118654752f));
}

__device__ __forceinline__ float sigmoidf_(float v) {
    return 1.0f / (1.0f + __expf(-v));
}

// ---------------- K0: fp32 -> bf16 weight conversion --------------------------
__global__ __launch_bounds__(256) void k_cvt_weights(
        const float* __restrict__ w1, const float* __restrict__ w2,
        const float* __restrict__ w3,
        unsigned short* __restrict__ o1, unsigned short* __restrict__ o2,
        unsigned short* __restrict__ o3, int n1, int n2, int n3) {
    int i = blockIdx.x * 256 + threadIdx.x;
    if (i < n1) o1[i] = f2bf(w1[i]);
    if (i < n2) o2[i] = f2bf(w2[i]);
    if (i < n3) o3[i] = f2bf(w3[i]);
}

// ---------------- K1: DualWalze -----------------------------------------------
__global__ __launch_bounds__(256) void k_walze(
        const float* __restrict__ x, const float* __restrict__ dww,
        const float* __restrict__ dwb, const float* __restrict__ shw,
        const float* __restrict__ shb, const float* __restrict__ mixw,
        const float* __restrict__ gamma, const float* __restrict__ beta,
        float* __restrict__ xw) {
    __shared__ float tile[1024];
    int bc = blockIdx.x;           // b*C + c
    int c = bc & (C_ - 1);
    int tid = threadIdx.x;
    const float* xp = x + (size_t)bc * 1024;
#pragma unroll
    for (int t = 0; t < 4; ++t) tile[tid + 256 * t] = xp[tid + 256 * t];
    __syncthreads();
    float wm[9], wsh[9];
#pragma unroll
    for (int t = 0; t < 9; ++t) { wm[t] = dww[c * 9 + t]; wsh[t] = shw[t]; }
    float mix = sigmoidf_(mixw[0]);
    float bmain = dwb[c], bsh = shb[0];
    float g = gamma[c], bt = beta[c];
    const float rs = rsqrtf(1.0f + 1e-5f);
#pragma unroll
    for (int t = 0; t < 4; ++t) {
        int l = tid + 256 * t;
        int h = l >> 5, w = l & 31;
        float accm = 0.f, accs = 0.f;
#pragma unroll
        for (int kh = 0; kh < 3; ++kh) {
            int hh = (h + kh + 31) & 31;
#pragma unroll
            for (int kw = 0; kw < 3; ++kw) {
                int ww = (w + kw + 31) & 31;
                float v = tile[hh * 32 + ww];
                accm += v * wm[kh * 3 + kw];
                accs += v * wsh[kh * 3 + kw];
            }
        }
        float combined = mix * (accm + bmain) + (1.f - mix) * (accs + bsh) + tile[l];
        float bn = g * combined * rs + bt;
        xw[(size_t)bc * 1024 + l] = gelu_exact(bn);
    }
}

// ---------------- K2: LDS-tiled transpose+pack to bf16 seq layout -------------
__global__ __launch_bounds__(256) void k_pack(
        const float* __restrict__ x, const float* __restrict__ xw,
        unsigned short* __restrict__ comb) {
    __shared__ float Tx[64 * 65];
    __shared__ float Tw[64 * 65];
    int b = blockIdx.z;
    int c0 = blockIdx.y * 64;
    int l0 = blockIdx.x * 64;
    int tid = threadIdx.x;
    for (int idx = tid; idx < 1024; idx += 256) {
        int cr = idx >> 4, f = idx & 15;
        size_t src = ((size_t)(b * C_ + c0 + cr) << 10) + l0 + f * 4;
        float4 vx = *(const float4*)(x + src);
        float4 vw = *(const float4*)(xw + src);
        *(float4*)&Tx[cr * 65 + f * 4] = vx;
        *(float4*)&Tw[cr * 65 + f * 4] = vw;
    }
    __syncthreads();
    for (int idx = tid; idx < 1024; idx += 256) {
        int lr = idx >> 4, f = idx & 15;
        ushort4 ux, uw;
        ux.x = f2bf(Tx[(4 * f + 0) * 65 + lr]);
        ux.y = f2bf(Tx[(4 * f + 1) * 65 + lr]);
        ux.z = f2bf(Tx[(4 * f + 2) * 65 + lr]);
        ux.w = f2bf(Tx[(4 * f + 3) * 65 + lr]);
        uw.x = f2bf(Tw[(4 * f + 0) * 65 + lr]);
        uw.y = f2bf(Tw[(4 * f + 1) * 65 + lr]);
        uw.z = f2bf(Tw[(4 * f + 2) * 65 + lr]);
        uw.w = f2bf(Tw[(4 * f + 3) * 65 + lr]);
        unsigned short* row = comb + (((size_t)(b << 10) + l0 + lr) << 10);
        *(ushort4*)(row + c0 + 4 * f) = ux;
        *(ushort4*)(row + 512 + c0 + 4 * f) = uw;
    }
}

// ---------------- K3: spike detector fused ------------------------------------
__global__ __launch_bounds__(256) void k_detector(
        const unsigned short* __restrict__ comb, const unsigned short* __restrict__ w1,
        const float* __restrict__ b1, const float* __restrict__ w2,
        const float* __restrict__ b2, float* __restrict__ sm) {
    __shared__ float red[64];
    int tid = threadIdx.x;
    int wave = tid >> 6, lane = tid & 63;
    int col = lane & 15, quad = lane >> 4;
    int m0 = blockIdx.x * 16;
    int koff = quad * 8;
    int nb0 = wave * 32, nb1 = nb0 + 16;
    const unsigned short* pa  = comb + (size_t)(m0 + col) * 1024 + koff;
    const unsigned short* pw0 = w1 + (size_t)(nb0 + col) * 1024 + koff;
    const unsigned short* pw1 = w1 + (size_t)(nb1 + col) * 1024 + koff;
    f32x4 acc0 = {0.f, 0.f, 0.f, 0.f}, acc1 = {0.f, 0.f, 0.f, 0.f};
    for (int k = 0; k < 1024; k += 32) {
        s16x8 a = ldg8(pa + k);
        acc0 = mfma_bf16(acc0, a, ldg8(pw0 + k));
        acc1 = mfma_bf16(acc1, a, ldg8(pw1 + k));
    }
    asm volatile("s_nop 7\ns_nop 7");
    float bia0 = b1[nb0 + col], bia1 = b1[nb1 + col];
    float wv0 = w2[nb0 + col], wv1 = w2[nb1 + col];
#pragma unroll
    for (int r = 0; r < 4; ++r) {
        float h0 = gelu_exact(acc0[r] + bia0);
        float h1 = gelu_exact(acc1[r] + bia1);
        float p = h0 * wv0 + h1 * wv1;
        p += __shfl_xor(p, 1);
        p += __shfl_xor(p, 2);
        p += __shfl_xor(p, 4);
        p += __shfl_xor(p, 8);
        if (col == 0) red[wave * 16 + quad * 4 + r] = p;
    }
    __syncthreads();
    if (tid < 16) {
        float s = red[tid] + red[16 + tid] + red[32 + tid] + red[48 + tid] + b2[0];
        sm[m0 + tid] = sigmoidf_(s);
    }
}

// ---------------- K4: qkv GEMM, staged 128x128xBK64, split bf16 out -----------
// out_hi everywhere; out_lo = bf16(v - hi) only for the q/k region (n < 1024)
__global__ __launch_bounds__(256) void k_gemm_qkv(
        const unsigned short* __restrict__ A,    // comb+512, lda=1024
        const unsigned short* __restrict__ Wt,   // [1536][512]
        const float* __restrict__ bias,
        unsigned short* __restrict__ out_hi, unsigned short* __restrict__ out_lo) {
    __shared__ unsigned short As[128 * 64];
    __shared__ unsigned short Bs[128 * 64];
    int tid = threadIdx.x;
    int wave = tid >> 6, lane = tid & 63;
    int col = lane & 15, quad = lane >> 4;
    int wr = wave & 1, wc = wave >> 1;
    int mb = blockIdx.y * 128, nb = blockIdx.x * 128;
    int srow = tid >> 3, sko = tid & 7;
    bool write_lo = (nb < 1024);   // q/k region only
    f32x4 acc[4][4] = {};
    for (int kb = 0; kb < 512; kb += 64) {
#pragma unroll
        for (int p = 0; p < 4; ++p) {
            int r = p * 32 + srow;
            async_cp16(A + (size_t)(mb + r) * 1024 + kb + sko * 8, &As[r * 64 + sko * 8]);
            async_cp16(Wt + (size_t)(nb + r) * 512 + kb + sko * 8, &Bs[r * 64 + sko * 8]);
        }
        __syncthreads();
#pragma unroll
        for (int ks = 0; ks < 64; ks += 32) {
            s16x8 a[4], b[4];
#pragma unroll
            for (int i = 0; i < 4; ++i)
                a[i] = *(const s16x8*)&As[(wr * 64 + i * 16 + col) * 64 + ks + quad * 8];
#pragma unroll
            for (int j = 0; j < 4; ++j)
                b[j] = *(const s16x8*)&Bs[(wc * 64 + j * 16 + col) * 64 + ks + quad * 8];
#pragma unroll
            for (int i = 0; i < 4; ++i)
#pragma unroll
                for (int j = 0; j < 4; ++j)
                    acc[i][j] = mfma_bf16(acc[i][j], a[i], b[j]);
        }
        __syncthreads();
    }
    asm volatile("s_nop 7\ns_nop 7");
#pragma unroll
    for (int i = 0; i < 4; ++i)
#pragma unroll
        for (int j = 0; j < 4; ++j) {
            int n = nb + wc * 64 + j * 16 + col;
            float bv = bias[n];
#pragma unroll
            for (int r = 0; r < 4; ++r) {
                int m = mb + wr * 64 + i * 16 + quad * 4 + r;
                float v = acc[i][j][r] + bv;
                unsigned short hi = f2bf(v);
                size_t idx = (size_t)m * 1536 + n;
                out_hi[idx] = hi;
                if (write_lo) out_lo[idx] = f2bf(v - bf2f(hi));
            }
        }
}

// ---------------- K5: windowed attention via MFMA, split-precision ------------
// S = qh.kh + qh.kl + ql.kh (fp32-accurate scores); P split hi/lo; O=(Ph+Pl).Vh
__global__ __launch_bounds__(256) void k_attn(
        const unsigned short* __restrict__ qkv_hi,
        const unsigned short* __restrict__ qkv_lo,
        unsigned short* __restrict__ ctx) {
    __shared__ unsigned short Vt[64 * 104];       // [d][key], ld=104
    __shared__ unsigned short Ph[4][16 * 104];    // per-wave P hi [m][key]
    __shared__ unsigned short Pl[4][16 * 104];    // per-wave P lo
    int b = blockIdx.z, h = blockIdx.y;
    int q0 = blockIdx.x * 64;
    int tid = threadIdx.x, wave = tid >> 6, lane = tid & 63;
    int col = lane & 15, quad = lane >> 4;
    int jlo_t = max(q0 - 16, 0);
    const unsigned short* baseh = qkv_hi + ((size_t)(b << 10)) * 1536;
    const unsigned short* basel = qkv_lo + ((size_t)(b << 10)) * 1536;
    // stage V^T (hi only): 12 key-groups x 64 d
#pragma unroll
    for (int it = 0; it < 3; ++it) {
        int slot = it * 256 + tid;
        int kg = slot >> 6, d = slot & 63;
        int key0 = jlo_t + kg * 8;
        unsigned short e[8];
#pragma unroll
        for (int t = 0; t < 8; ++t)
            e[t] = baseh[(size_t)min(key0 + t, 1023) * 1536 + 1024 + h * 64 + d];
        ushort4 w0 = {e[0], e[1], e[2], e[3]}, w1 = {e[4], e[5], e[6], e[7]};
        *(ushort4*)&Vt[d * 104 + kg * 8] = w0;
        *(ushort4*)&Vt[d * 104 + kg * 8 + 4] = w1;
    }
    __syncthreads();
    // Q A-frags hi+lo
    size_t qoff = (size_t)(q0 + wave * 16 + col) * 1536 + h * 64;
    s16x8 aq0h = ldg8(baseh + qoff + quad * 8);
    s16x8 aq1h = ldg8(baseh + qoff + 32 + quad * 8);
    s16x8 aq0l = ldg8(basel + qoff + quad * 8);
    s16x8 aq1l = ldg8(basel + qoff + 32 + quad * 8);
    // S over 6 key-tiles of 16
    f32x4 S[6];
#pragma unroll
    for (int nt = 0; nt < 6; ++nt) {
        size_t koffb = (size_t)min(jlo_t + nt * 16 + col, 1023) * 1536 + 512 + h * 64;
        s16x8 kh0 = ldg8(baseh + koffb + quad * 8);
        s16x8 kh1 = ldg8(baseh + koffb + 32 + quad * 8);
        s16x8 kl0 = ldg8(basel + koffb + quad * 8);
        s16x8 kl1 = ldg8(basel + koffb + 32 + quad * 8);
        f32x4 z = {0.f, 0.f, 0.f, 0.f};
        z = mfma_bf16(z, aq0h, kh0);
        z = mfma_bf16(z, aq1h, kh1);
        z = mfma_bf16(z, aq0h, kl0);
        z = mfma_bf16(z, aq1h, kl1);
        z = mfma_bf16(z, aq0l, kh0);
        z = mfma_bf16(z, aq1l, kh1);
        S[nt] = z;
    }
    asm volatile("s_nop 7\ns_nop 7");
    // masked softmax per row r
    int i_base = q0 + wave * 16 + quad * 4;
    float mx[4] = {-1e30f, -1e30f, -1e30f, -1e30f};
#pragma unroll
    for (int nt = 0; nt < 6; ++nt) {
        int j = jlo_t + nt * 16 + col;
#pragma unroll
        for (int r = 0; r < 4; ++r) {
            int i = i_base + r;
            bool ok = (j <= 1023) && (j >= i - 16) && (j <= i + 16);
            float s = ok ? S[nt][r] * 0.125f : -1e30f;
            S[nt][r] = s;
            mx[r] = fmaxf(mx[r], s);
        }
    }
#pragma unroll
    for (int r = 0; r < 4; ++r) {
        mx[r] = fmaxf(mx[r], __shfl_xor(mx[r], 1));
        mx[r] = fmaxf(mx[r], __shfl_xor(mx[r], 2));
        mx[r] = fmaxf(mx[r], __shfl_xor(mx[r], 4));
        mx[r] = fmaxf(mx[r], __shfl_xor(mx[r], 8));
    }
    float sum[4] = {0.f, 0.f, 0.f, 0.f};
#pragma unroll
    for (int nt = 0; nt < 6; ++nt)
#pragma unroll
        for (int r = 0; r < 4; ++r) {
            float p = __expf(S[nt][r] - mx[r]);
            S[nt][r] = p;
            sum[r] += p;
        }
#pragma unroll
    for (int r = 0; r < 4; ++r) {
        sum[r] += __shfl_xor(sum[r], 1);
        sum[r] += __shfl_xor(sum[r], 2);
        sum[r] += __shfl_xor(sum[r], 4);
        sum[r] += __shfl_xor(sum[r], 8);
        sum[r] = 1.f / sum[r];
    }
    // normalized P -> LDS, split hi/lo
#pragma unroll
    for (int nt = 0; nt < 6; ++nt)
#pragma unroll
        for (int r = 0; r < 4; ++r) {
            float pv = S[nt][r] * sum[r];
            unsigned short hi = f2bf(pv);
            Ph[wave][(quad * 4 + r) * 104 + nt * 16 + col] = hi;
            Pl[wave][(quad * 4 + r) * 104 + nt * 16 + col] = f2bf(pv - bf2f(hi));
        }
    asm volatile("s_waitcnt lgkmcnt(0)" ::: "memory");
    // O = (Ph + Pl) V
    f32x4 O[4] = {};
#pragma unroll
    for (int ks = 0; ks < 96; ks += 32) {
        s16x8 aph = *(const s16x8*)&Ph[wave][col * 104 + ks + quad * 8];
        s16x8 apl = *(const s16x8*)&Pl[wave][col * 104 + ks + quad * 8];
#pragma unroll
        for (int nt = 0; nt < 4; ++nt) {
            s16x8 bv = *(const s16x8*)&Vt[(nt * 16 + col) * 104 + ks + quad * 8];
            O[nt] = mfma_bf16(O[nt], aph, bv);
            O[nt] = mfma_bf16(O[nt], apl, bv);
        }
    }
    asm volatile("s_nop 7\ns_nop 7");
#pragma unroll
    for (int nt = 0; nt < 4; ++nt)
#pragma unroll
        for (int r = 0; r < 4; ++r) {
            int i = i_base + r;
            ctx[((size_t)(b << 10) + i) * 512 + h * 64 + nt * 16 + col] = f2bf(O[nt][r]);
        }
}

// ---------------- K6: out-proj GEMM staged + gated combine --------------------
// A = out_proj_w [512][512] (M=channels), B = ctx [8192][512] (N=seq)
__global__ __launch_bounds__(256) void k_out_combine(
        const unsigned short* __restrict__ Wt, const unsigned short* __restrict__ Actx,
        const float* __restrict__ bias, const float* __restrict__ xw,
        const float* __restrict__ sm, float* __restrict__ out) {
    __shared__ unsigned short As[128 * 64];
    __shared__ unsigned short Bs[128 * 64];
    int tid = threadIdx.x;
    int wave = tid >> 6, lane = tid & 63;
    int col = lane & 15, quad = lane >> 4;
    int wr = wave & 1, wc = wave >> 1;
    int mb = blockIdx.y * 128, nb = blockIdx.x * 128;
    int srow = tid >> 3, sko = tid & 7;
    f32x4 acc[4][4] = {};
    for (int kb = 0; kb < 512; kb += 64) {
#pragma unroll
        for (int p = 0; p < 4; ++p) {
            int r = p * 32 + srow;
            async_cp16(Wt + (size_t)(mb + r) * 512 + kb + sko * 8, &As[r * 64 + sko * 8]);
            async_cp16(Actx + (size_t)(nb + r) * 512 + kb + sko * 8, &Bs[r * 64 + sko * 8]);
        }
        __syncthreads();
#pragma unroll
        for (int ks = 0; ks < 64; ks += 32) {
            s16x8 a[4], b[4];
#pragma unroll
            for (int i = 0; i < 4; ++i)
                a[i] = *(const s16x8*)&As[(wr * 64 + i * 16 + col) * 64 + ks + quad * 8];
#pragma unroll
            for (int j = 0; j < 4; ++j)
                b[j] = *(const s16x8*)&Bs[(wc * 64 + j * 16 + col) * 64 + ks + quad * 8];
#pragma unroll
            for (int i = 0; i < 4; ++i)
#pragma unroll
                for (int j = 0; j < 4; ++j)
                    acc[i][j] = mfma_bf16(acc[i][j], a[i], b[j]);
        }
        __syncthreads();
    }
    asm volatile("s_nop 7\ns_nop 7");
#pragma unroll
    for (int i = 0; i < 4; ++i)
#pragma unroll
        for (int j = 0; j < 4; ++j) {
            int seq = nb + wc * 64 + j * 16 + col;
            int bb = seq >> 10, l = seq & 1023;
            float smv = sm[seq];
#pragma unroll
            for (int r = 0; r < 4; ++r) {
                int c = mb + wr * 64 + i * 16 + quad * 4 + r;
                float v = acc[i][j][r] + bias[c];
                size_t oidx = ((size_t)(bb * C_ + c) << 10) + l;
                out[oidx] = xw[oidx] + smv * v;
            }
        }
}

extern "C" void kernel_launch(void* const* d_in, const int* in_sizes, int n_in,
                              void* d_out, int out_size, void* d_ws, size_t ws_size,
                              hipStream_t stream) {
    const float* x      = (const float*)d_in[0];
    const float* dw_w   = (const float*)d_in[1];
    const float* dw_b   = (const float*)d_in[2];
    const float* sh_w   = (const float*)d_in[3];
    const float* sh_b   = (const float*)d_in[4];
    const float* mix_w  = (const float*)d_in[5];
    const float* bn_g   = (const float*)d_in[6];
    const float* bn_b   = (const float*)d_in[7];
    const float* det_w1 = (const float*)d_in[8];
    const float* det_b1 = (const float*)d_in[9];
    const float* det_w2 = (const float*)d_in[10];
    const float* det_b2 = (const float*)d_in[11];
    const float* inp_w  = (const float*)d_in[12];
    const float* inp_b  = (const float*)d_in[13];
    const float* outp_w = (const float*)d_in[14];
    const float* outp_b = (const float*)d_in[15];
    float* out = (float*)d_out;

    char* ws = (char*)d_ws;
    size_t off = 0;
    auto alloc = [&](size_t bytes) -> void* {
        void* p = ws + off;
        off += (bytes + 255) & ~(size_t)255;
        return p;
    };
    float* xw             = (float*)alloc((size_t)M_ * C_ * 4);
    unsigned short* comb  = (unsigned short*)alloc((size_t)M_ * 1024 * 2);
    unsigned short* qkvh  = (unsigned short*)alloc((size_t)M_ * 1536 * 2);
    unsigned short* qkvl  = (unsigned short*)alloc((size_t)M_ * 1536 * 2);
    unsigned short* ctx   = (unsigned short*)alloc((size_t)M_ * 512 * 2);
    float* smask          = (float*)alloc((size_t)M_ * 4);
    unsigned short* w1b   = (unsigned short*)alloc(131072 * 2);
    unsigned short* inwb  = (unsigned short*)alloc(786432 * 2);
    unsigned short* outwb = (unsigned short*)alloc(262144 * 2);
    (void)ws_size; (void)in_sizes; (void)n_in; (void)out_size;

    k_cvt_weights<<<3072, 256, 0, stream>>>(det_w1, inp_w, outp_w, w1b, inwb, outwb,
                                            131072, 786432, 262144);
    k_walze<<<B_ * C_, 256, 0, stream>>>(x, dw_w, dw_b, sh_w, sh_b, mix_w, bn_g, bn_b, xw);
    k_pack<<<dim3(16, 8, 8), 256, 0, stream>>>(x, xw, comb);
    k_detector<<<M_ / 16, 256, 0, stream>>>(comb, w1b, det_b1, det_w2, det_b2, smask);
    k_gemm_qkv<<<dim3(1536 / 128, M_ / 128), 256, 0, stream>>>(comb + 512, inwb, inp_b,
                                                               qkvh, qkvl);
    k_attn<<<dim3(16, NH_, B_), 256, 0, stream>>>(qkvh, qkvl, ctx);
    k_out_combine<<<dim3(M_ / 128, C_ / 128), 256, 0, stream>>>(outwb, ctx, outp_b,
                                                                xw, smask, out);
}

// Round 6
// 197.360 us; speedup vs baseline: 2.3057x; 1.0122x over previous
//
#include <hip/hip_runtime.h>

#define B_ 8
#define C_ 512
#define H_ 32
#define W_ 32
#define L_ 1024
#define M_ 8192   // B*L
#define NH_ 8
#define HD_ 64

typedef float f32x4 __attribute__((ext_vector_type(4)));
typedef short s16x8 __attribute__((ext_vector_type(8)));

// MFMA 16x16x32 bf16. C/D: col=lane&15 (n), row=(lane>>4)*4+reg (m).
// A frag: row m=lane&15, k=(lane>>4)*8+j ; B frag from B^T [n][k]: row n=lane&15.
__device__ __forceinline__ f32x4 mfma_bf16(f32x4 acc, s16x8 a, s16x8 b) {
    asm("v_mfma_f32_16x16x32_bf16 %0, %1, %2, %0" : "+v"(acc) : "v"(a), "v"(b));
    return acc;
}

__device__ __forceinline__ s16x8 ldg8(const unsigned short* p) {
    return *(const s16x8*)p;
}

typedef __attribute__((address_space(1))) const unsigned int glob_u32;
typedef __attribute__((address_space(3))) unsigned int lds_u32;
__device__ __forceinline__ void async_cp16(const void* g, void* l) {
    __builtin_amdgcn_global_load_lds((glob_u32*)g, (lds_u32*)l, 16, 0, 0);
}

__device__ __forceinline__ unsigned short f2bf(float f) {
    unsigned int u = __float_as_uint(f);
    unsigned int r = (u + 0x7FFFu + ((u >> 16) & 1u)) >> 16;
    return (unsigned short)r;
}

__device__ __forceinline__ float bf2f(unsigned short u) {
    return __uint_as_float(((unsigned int)u) << 16);
}

__device__ __forceinline__ float gelu_exact(float v) {
    return 0.5f * v * (1.0f + erff(v * 0.70710678118654752f));
}

__device__ __forceinline__ float sigmoidf_(float v) {
    return 1.0f / (1.0f + __expf(-v));
}

// ---------------- K0: fp32 -> bf16 weight conversion --------------------------
__global__ __launch_bounds__(256) void k_cvt_weights(
        const float* __restrict__ w1, const float* __restrict__ w2,
        const float* __restrict__ w3,
        unsigned short* __restrict__ o1, unsigned short* __restrict__ o2,
        unsigned short* __restrict__ o3, int n1, int n2, int n3) {
    int i = blockIdx.x * 256 + threadIdx.x;
    if (i < n1) o1[i] = f2bf(w1[i]);
    if (i < n2) o2[i] = f2bf(w2[i]);
    if (i < n3) o3[i] = f2bf(w3[i]);
}

// ---------------- K1: DualWalze -----------------------------------------------
__global__ __launch_bounds__(256) void k_walze(
        const float* __restrict__ x, const float* __restrict__ dww,
        const float* __restrict__ dwb, const float* __restrict__ shw,
        const float* __restrict__ shb, const float* __restrict__ mixw,
        const float* __restrict__ gamma, const float* __restrict__ beta,
        float* __restrict__ xw) {
    __shared__ float tile[1024];
    int bc = blockIdx.x;           // b*C + c
    int c = bc & (C_ - 1);
    int tid = threadIdx.x;
    const float* xp = x + (size_t)bc * 1024;
#pragma unroll
    for (int t = 0; t < 4; ++t) tile[tid + 256 * t] = xp[tid + 256 * t];
    __syncthreads();
    float wm[9], wsh[9];
#pragma unroll
    for (int t = 0; t < 9; ++t) { wm[t] = dww[c * 9 + t]; wsh[t] = shw[t]; }
    float mix = sigmoidf_(mixw[0]);
    float bmain = dwb[c], bsh = shb[0];
    float g = gamma[c], bt = beta[c];
    const float rs = rsqrtf(1.0f + 1e-5f);
#pragma unroll
    for (int t = 0; t < 4; ++t) {
        int l = tid + 256 * t;
        int h = l >> 5, w = l & 31;
        float accm = 0.f, accs = 0.f;
#pragma unroll
        for (int kh = 0; kh < 3; ++kh) {
            int hh = (h + kh + 31) & 31;
#pragma unroll
            for (int kw = 0; kw < 3; ++kw) {
                int ww = (w + kw + 31) & 31;
                float v = tile[hh * 32 + ww];
                accm += v * wm[kh * 3 + kw];
                accs += v * wsh[kh * 3 + kw];
            }
        }
        float combined = mix * (accm + bmain) + (1.f - mix) * (accs + bsh) + tile[l];
        float bn = g * combined * rs + bt;
        xw[(size_t)bc * 1024 + l] = gelu_exact(bn);
    }
}

// ---------------- K2: LDS-tiled transpose+pack to bf16 seq layout -------------
__global__ __launch_bounds__(256) void k_pack(
        const float* __restrict__ x, const float* __restrict__ xw,
        unsigned short* __restrict__ comb) {
    __shared__ float Tx[64 * 65];
    __shared__ float Tw[64 * 65];
    int b = blockIdx.z;
    int c0 = blockIdx.y * 64;
    int l0 = blockIdx.x * 64;
    int tid = threadIdx.x;
    for (int idx = tid; idx < 1024; idx += 256) {
        int cr = idx >> 4, f = idx & 15;
        size_t src = ((size_t)(b * C_ + c0 + cr) << 10) + l0 + f * 4;
        float4 vx = *(const float4*)(x + src);
        float4 vw = *(const float4*)(xw + src);
        *(float4*)&Tx[cr * 65 + f * 4] = vx;
        *(float4*)&Tw[cr * 65 + f * 4] = vw;
    }
    __syncthreads();
    for (int idx = tid; idx < 1024; idx += 256) {
        int lr = idx >> 4, f = idx & 15;
        ushort4 ux, uw;
        ux.x = f2bf(Tx[(4 * f + 0) * 65 + lr]);
        ux.y = f2bf(Tx[(4 * f + 1) * 65 + lr]);
        ux.z = f2bf(Tx[(4 * f + 2) * 65 + lr]);
        ux.w = f2bf(Tx[(4 * f + 3) * 65 + lr]);
        uw.x = f2bf(Tw[(4 * f + 0) * 65 + lr]);
        uw.y = f2bf(Tw[(4 * f + 1) * 65 + lr]);
        uw.z = f2bf(Tw[(4 * f + 2) * 65 + lr]);
        uw.w = f2bf(Tw[(4 * f + 3) * 65 + lr]);
        unsigned short* row = comb + (((size_t)(b << 10) + l0 + lr) << 10);
        *(ushort4*)(row + c0 + 4 * f) = ux;
        *(ushort4*)(row + 512 + c0 + 4 * f) = uw;
    }
}

// ---------------- K3: spike detector fused ------------------------------------
__global__ __launch_bounds__(256) void k_detector(
        const unsigned short* __restrict__ comb, const unsigned short* __restrict__ w1,
        const float* __restrict__ b1, const float* __restrict__ w2,
        const float* __restrict__ b2, float* __restrict__ sm) {
    __shared__ float red[64];
    int tid = threadIdx.x;
    int wave = tid >> 6, lane = tid & 63;
    int col = lane & 15, quad = lane >> 4;
    int m0 = blockIdx.x * 16;
    int koff = quad * 8;
    int nb0 = wave * 32, nb1 = nb0 + 16;
    const unsigned short* pa  = comb + (size_t)(m0 + col) * 1024 + koff;
    const unsigned short* pw0 = w1 + (size_t)(nb0 + col) * 1024 + koff;
    const unsigned short* pw1 = w1 + (size_t)(nb1 + col) * 1024 + koff;
    f32x4 acc0 = {0.f, 0.f, 0.f, 0.f}, acc1 = {0.f, 0.f, 0.f, 0.f};
    for (int k = 0; k < 1024; k += 32) {
        s16x8 a = ldg8(pa + k);
        acc0 = mfma_bf16(acc0, a, ldg8(pw0 + k));
        acc1 = mfma_bf16(acc1, a, ldg8(pw1 + k));
    }
    asm volatile("s_nop 7\ns_nop 7");
    float bia0 = b1[nb0 + col], bia1 = b1[nb1 + col];
    float wv0 = w2[nb0 + col], wv1 = w2[nb1 + col];
#pragma unroll
    for (int r = 0; r < 4; ++r) {
        float h0 = gelu_exact(acc0[r] + bia0);
        float h1 = gelu_exact(acc1[r] + bia1);
        float p = h0 * wv0 + h1 * wv1;
        p += __shfl_xor(p, 1);
        p += __shfl_xor(p, 2);
        p += __shfl_xor(p, 4);
        p += __shfl_xor(p, 8);
        if (col == 0) red[wave * 16 + quad * 4 + r] = p;
    }
    __syncthreads();
    if (tid < 16) {
        float s = red[tid] + red[16 + tid] + red[32 + tid] + red[48 + tid] + b2[0];
        sm[m0 + tid] = sigmoidf_(s);
    }
}

// ---------------- K4: qkv GEMM, staged 128x128xBK64, split bf16 out -----------
// out_hi = bf16(v); out_lo = bf16(v - hi) for the full 1536 row (q,k AND v)
__global__ __launch_bounds__(256) void k_gemm_qkv(
        const unsigned short* __restrict__ A,    // comb+512, lda=1024
        const unsigned short* __restrict__ Wt,   // [1536][512]
        const float* __restrict__ bias,
        unsigned short* __restrict__ out_hi, unsigned short* __restrict__ out_lo) {
    __shared__ unsigned short As[128 * 64];
    __shared__ unsigned short Bs[128 * 64];
    int tid = threadIdx.x;
    int wave = tid >> 6, lane = tid & 63;
    int col = lane & 15, quad = lane >> 4;
    int wr = wave & 1, wc = wave >> 1;
    int mb = blockIdx.y * 128, nb = blockIdx.x * 128;
    int srow = tid >> 3, sko = tid & 7;
    f32x4 acc[4][4] = {};
    for (int kb = 0; kb < 512; kb += 64) {
#pragma unroll
        for (int p = 0; p < 4; ++p) {
            int r = p * 32 + srow;
            async_cp16(A + (size_t)(mb + r) * 1024 + kb + sko * 8, &As[r * 64 + sko * 8]);
            async_cp16(Wt + (size_t)(nb + r) * 512 + kb + sko * 8, &Bs[r * 64 + sko * 8]);
        }
        __syncthreads();
#pragma unroll
        for (int ks = 0; ks < 64; ks += 32) {
            s16x8 a[4], b[4];
#pragma unroll
            for (int i = 0; i < 4; ++i)
                a[i] = *(const s16x8*)&As[(wr * 64 + i * 16 + col) * 64 + ks + quad * 8];
#pragma unroll
            for (int j = 0; j < 4; ++j)
                b[j] = *(const s16x8*)&Bs[(wc * 64 + j * 16 + col) * 64 + ks + quad * 8];
#pragma unroll
            for (int i = 0; i < 4; ++i)
#pragma unroll
                for (int j = 0; j < 4; ++j)
                    acc[i][j] = mfma_bf16(acc[i][j], a[i], b[j]);
        }
        __syncthreads();
    }
    asm volatile("s_nop 7\ns_nop 7");
#pragma unroll
    for (int i = 0; i < 4; ++i)
#pragma unroll
        for (int j = 0; j < 4; ++j) {
            int n = nb + wc * 64 + j * 16 + col;
            float bv = bias[n];
#pragma unroll
            for (int r = 0; r < 4; ++r) {
                int m = mb + wr * 64 + i * 16 + quad * 4 + r;
                float v = acc[i][j][r] + bv;
                unsigned short hi = f2bf(v);
                size_t idx = (size_t)m * 1536 + n;
                out_hi[idx] = hi;
                out_lo[idx] = f2bf(v - bf2f(hi));
            }
        }
}

// ---------------- K5: windowed attention via MFMA, split-precision ------------
// S = qh.kh + qh.kl + ql.kh ; P NORMALIZED then split hi/lo (round-4 structure);
// O = Ph.Vh + Pl.Vh + Ph.Vl written directly.
__global__ __launch_bounds__(256) void k_attn(
        const unsigned short* __restrict__ qkv_hi,
        const unsigned short* __restrict__ qkv_lo,
        unsigned short* __restrict__ ctx) {
    __shared__ unsigned short Vth[64 * 104];      // V hi [d][key], ld=104
    __shared__ unsigned short Vtl[64 * 104];      // V lo
    __shared__ unsigned short Ph[4][16 * 104];    // per-wave P hi [m][key]
    __shared__ unsigned short Pl[4][16 * 104];    // per-wave P lo
    int b = blockIdx.z, h = blockIdx.y;
    int q0 = blockIdx.x * 64;
    int tid = threadIdx.x, wave = tid >> 6, lane = tid & 63;
    int col = lane & 15, quad = lane >> 4;
    int jlo_t = max(q0 - 16, 0);
    const unsigned short* baseh = qkv_hi + ((size_t)(b << 10)) * 1536;
    const unsigned short* basel = qkv_lo + ((size_t)(b << 10)) * 1536;
    // stage V^T hi and lo: 12 key-groups x 64 d
#pragma unroll
    for (int it = 0; it < 3; ++it) {
        int slot = it * 256 + tid;
        int kg = slot >> 6, d = slot & 63;
        int key0 = jlo_t + kg * 8;
        unsigned short eh[8], el[8];
#pragma unroll
        for (int t = 0; t < 8; ++t) {
            size_t ro = (size_t)min(key0 + t, 1023) * 1536 + 1024 + h * 64 + d;
            eh[t] = baseh[ro];
            el[t] = basel[ro];
        }
        ushort4 h0 = {eh[0], eh[1], eh[2], eh[3]}, h1 = {eh[4], eh[5], eh[6], eh[7]};
        ushort4 l0 = {el[0], el[1], el[2], el[3]}, l1 = {el[4], el[5], el[6], el[7]};
        *(ushort4*)&Vth[d * 104 + kg * 8] = h0;
        *(ushort4*)&Vth[d * 104 + kg * 8 + 4] = h1;
        *(ushort4*)&Vtl[d * 104 + kg * 8] = l0;
        *(ushort4*)&Vtl[d * 104 + kg * 8 + 4] = l1;
    }
    __syncthreads();
    // Q A-frags hi+lo
    size_t qoff = (size_t)(q0 + wave * 16 + col) * 1536 + h * 64;
    s16x8 aq0h = ldg8(baseh + qoff + quad * 8);
    s16x8 aq1h = ldg8(baseh + qoff + 32 + quad * 8);
    s16x8 aq0l = ldg8(basel + qoff + quad * 8);
    s16x8 aq1l = ldg8(basel + qoff + 32 + quad * 8);
    // S over 6 key-tiles of 16
    f32x4 S[6];
#pragma unroll
    for (int nt = 0; nt < 6; ++nt) {
        size_t koffb = (size_t)min(jlo_t + nt * 16 + col, 1023) * 1536 + 512 + h * 64;
        s16x8 kh0 = ldg8(baseh + koffb + quad * 8);
        s16x8 kh1 = ldg8(baseh + koffb + 32 + quad * 8);
        s16x8 kl0 = ldg8(basel + koffb + quad * 8);
        s16x8 kl1 = ldg8(basel + koffb + 32 + quad * 8);
        f32x4 z = {0.f, 0.f, 0.f, 0.f};
        z = mfma_bf16(z, aq0h, kh0);
        z = mfma_bf16(z, aq1h, kh1);
        z = mfma_bf16(z, aq0h, kl0);
        z = mfma_bf16(z, aq1h, kl1);
        z = mfma_bf16(z, aq0l, kh0);
        z = mfma_bf16(z, aq1l, kh1);
        S[nt] = z;
    }
    asm volatile("s_nop 7\ns_nop 7");
    // masked softmax per row r
    int i_base = q0 + wave * 16 + quad * 4;
    float mx[4] = {-1e30f, -1e30f, -1e30f, -1e30f};
#pragma unroll
    for (int nt = 0; nt < 6; ++nt) {
        int j = jlo_t + nt * 16 + col;
#pragma unroll
        for (int r = 0; r < 4; ++r) {
            int i = i_base + r;
            bool ok = (j <= 1023) && (j >= i - 16) && (j <= i + 16);
            float s = ok ? S[nt][r] * 0.125f : -1e30f;
            S[nt][r] = s;
            mx[r] = fmaxf(mx[r], s);
        }
    }
#pragma unroll
    for (int r = 0; r < 4; ++r) {
        mx[r] = fmaxf(mx[r], __shfl_xor(mx[r], 1));
        mx[r] = fmaxf(mx[r], __shfl_xor(mx[r], 2));
        mx[r] = fmaxf(mx[r], __shfl_xor(mx[r], 4));
        mx[r] = fmaxf(mx[r], __shfl_xor(mx[r], 8));
    }
    float sum[4] = {0.f, 0.f, 0.f, 0.f};
#pragma unroll
    for (int nt = 0; nt < 6; ++nt)
#pragma unroll
        for (int r = 0; r < 4; ++r) {
            float p = __expf(S[nt][r] - mx[r]);
            S[nt][r] = p;
            sum[r] += p;
        }
#pragma unroll
    for (int r = 0; r < 4; ++r) {
        sum[r] += __shfl_xor(sum[r], 1);
        sum[r] += __shfl_xor(sum[r], 2);
        sum[r] += __shfl_xor(sum[r], 4);
        sum[r] += __shfl_xor(sum[r], 8);
        sum[r] = 1.f / sum[r];
    }
    // NORMALIZED P -> LDS, split hi/lo (round-4 structure)
#pragma unroll
    for (int nt = 0; nt < 6; ++nt)
#pragma unroll
        for (int r = 0; r < 4; ++r) {
            float pv = S[nt][r] * sum[r];
            unsigned short hi = f2bf(pv);
            Ph[wave][(quad * 4 + r) * 104 + nt * 16 + col] = hi;
            Pl[wave][(quad * 4 + r) * 104 + nt * 16 + col] = f2bf(pv - bf2f(hi));
        }
    __syncthreads();   // hard ordering: P LDS-writes visible before vector reloads
    // O = Ph.Vh + Pl.Vh + Ph.Vl
    f32x4 O[4] = {};
#pragma unroll
    for (int ks = 0; ks < 96; ks += 32) {
        s16x8 aph = *(const s16x8*)&Ph[wave][col * 104 + ks + quad * 8];
        s16x8 apl = *(const s16x8*)&Pl[wave][col * 104 + ks + quad * 8];
#pragma unroll
        for (int nt = 0; nt < 4; ++nt) {
            s16x8 bvh = *(const s16x8*)&Vth[(nt * 16 + col) * 104 + ks + quad * 8];
            s16x8 bvl = *(const s16x8*)&Vtl[(nt * 16 + col) * 104 + ks + quad * 8];
            O[nt] = mfma_bf16(O[nt], aph, bvh);
            O[nt] = mfma_bf16(O[nt], apl, bvh);
            O[nt] = mfma_bf16(O[nt], aph, bvl);
        }
    }
    asm volatile("s_nop 7\ns_nop 7");
#pragma unroll
    for (int nt = 0; nt < 4; ++nt)
#pragma unroll
        for (int r = 0; r < 4; ++r) {
            int i = i_base + r;
            ctx[((size_t)(b << 10) + i) * 512 + h * 64 + nt * 16 + col] = f2bf(O[nt][r]);
        }
}

// ---------------- K6: out-proj GEMM staged + gated combine --------------------
// A = out_proj_w [512][512] (M=channels), B = ctx [8192][512] (N=seq)
__global__ __launch_bounds__(256) void k_out_combine(
        const unsigned short* __restrict__ Wt, const unsigned short* __restrict__ Actx,
        const float* __restrict__ bias, const float* __restrict__ xw,
        const float* __restrict__ sm, float* __restrict__ out) {
    __shared__ unsigned short As[128 * 64];
    __shared__ unsigned short Bs[128 * 64];
    int tid = threadIdx.x;
    int wave = tid >> 6, lane = tid & 63;
    int col = lane & 15, quad = lane >> 4;
    int wr = wave & 1, wc = wave >> 1;
    int mb = blockIdx.y * 128, nb = blockIdx.x * 128;
    int srow = tid >> 3, sko = tid & 7;
    f32x4 acc[4][4] = {};
    for (int kb = 0; kb < 512; kb += 64) {
#pragma unroll
        for (int p = 0; p < 4; ++p) {
            int r = p * 32 + srow;
            async_cp16(Wt + (size_t)(mb + r) * 512 + kb + sko * 8, &As[r * 64 + sko * 8]);
            async_cp16(Actx + (size_t)(nb + r) * 512 + kb + sko * 8, &Bs[r * 64 + sko * 8]);
        }
        __syncthreads();
#pragma unroll
        for (int ks = 0; ks < 64; ks += 32) {
            s16x8 a[4], b[4];
#pragma unroll
            for (int i = 0; i < 4; ++i)
                a[i] = *(const s16x8*)&As[(wr * 64 + i * 16 + col) * 64 + ks + quad * 8];
#pragma unroll
            for (int j = 0; j < 4; ++j)
                b[j] = *(const s16x8*)&Bs[(wc * 64 + j * 16 + col) * 64 + ks + quad * 8];
#pragma unroll
            for (int i = 0; i < 4; ++i)
#pragma unroll
                for (int j = 0; j < 4; ++j)
                    acc[i][j] = mfma_bf16(acc[i][j], a[i], b[j]);
        }
        __syncthreads();
    }
    asm volatile("s_nop 7\ns_nop 7");
#pragma unroll
    for (int i = 0; i < 4; ++i)
#pragma unroll
        for (int j = 0; j < 4; ++j) {
            int seq = nb + wc * 64 + j * 16 + col;
            int bb = seq >> 10, l = seq & 1023;
            float smv = sm[seq];
#pragma unroll
            for (int r = 0; r < 4; ++r) {
                int c = mb + wr * 64 + i * 16 + quad * 4 + r;
                float v = acc[i][j][r] + bias[c];
                size_t oidx = ((size_t)(bb * C_ + c) << 10) + l;
                out[oidx] = xw[oidx] + smv * v;
            }
        }
}

extern "C" void kernel_launch(void* const* d_in, const int* in_sizes, int n_in,
                              void* d_out, int out_size, void* d_ws, size_t ws_size,
                              hipStream_t stream) {
    const float* x      = (const float*)d_in[0];
    const float* dw_w   = (const float*)d_in[1];
    const float* dw_b   = (const float*)d_in[2];
    const float* sh_w   = (const float*)d_in[3];
    const float* sh_b   = (const float*)d_in[4];
    const float* mix_w  = (const float*)d_in[5];
    const float* bn_g   = (const float*)d_in[6];
    const float* bn_b   = (const float*)d_in[7];
    const float* det_w1 = (const float*)d_in[8];
    const float* det_b1 = (const float*)d_in[9];
    const float* det_w2 = (const float*)d_in[10];
    const float* det_b2 = (const float*)d_in[11];
    const float* inp_w  = (const float*)d_in[12];
    const float* inp_b  = (const float*)d_in[13];
    const float* outp_w = (const float*)d_in[14];
    const float* outp_b = (const float*)d_in[15];
    float* out = (float*)d_out;

    char* ws = (char*)d_ws;
    size_t off = 0;
    auto alloc = [&](size_t bytes) -> void* {
        void* p = ws + off;
        off += (bytes + 255) & ~(size_t)255;
        return p;
    };
    float* xw             = (float*)alloc((size_t)M_ * C_ * 4);
    unsigned short* comb  = (unsigned short*)alloc((size_t)M_ * 1024 * 2);
    unsigned short* qkvh  = (unsigned short*)alloc((size_t)M_ * 1536 * 2);
    unsigned short* qkvl  = (unsigned short*)alloc((size_t)M_ * 1536 * 2);
    unsigned short* ctx   = (unsigned short*)alloc((size_t)M_ * 512 * 2);
    float* smask          = (float*)alloc((size_t)M_ * 4);
    unsigned short* w1b   = (unsigned short*)alloc(131072 * 2);
    unsigned short* inwb  = (unsigned short*)alloc(786432 * 2);
    unsigned short* outwb = (unsigned short*)alloc(262144 * 2);
    (void)ws_size; (void)in_sizes; (void)n_in; (void)out_size;

    k_cvt_weights<<<3072, 256, 0, stream>>>(det_w1, inp_w, outp_w, w1b, inwb, outwb,
                                            131072, 786432, 262144);
    k_walze<<<B_ * C_, 256, 0, stream>>>(x, dw_w, dw_b, sh_w, sh_b, mix_w, bn_g, bn_b, xw);
    k_pack<<<dim3(16, 8, 8), 256, 0, stream>>>(x, xw, comb);
    k_detector<<<M_ / 16, 256, 0, stream>>>(comb, w1b, det_b1, det_w2, det_b2, smask);
    k_gemm_qkv<<<dim3(1536 / 128, M_ / 128), 256, 0, stream>>>(comb + 512, inwb, inp_b,
                                                               qkvh, qkvl);
    k_attn<<<dim3(16, NH_, B_), 256, 0, stream>>>(qkvh, qkvl, ctx);
    k_out_combine<<<dim3(M_ / 128, C_ / 128), 256, 0, stream>>>(outwb, ctx, outp_b,
                                                                xw, smask, out);
}